// Round 4
// baseline (970.132 us; speedup 1.0000x reference)
//
#include <hip/hip_runtime.h>

// ---------------------------------------------------------------------------
// PAM_Module_Dep: dual-modality position attention. B=4, C=512, N=4096, CQ=64.
// Round 4: occupancy fix (round 3 was latency-bound at 23.8% occupancy,
// MfmaUtil 10%: grid 256 blocks = exactly 1 block/CU).
//  - attn: 32 Q-rows/block, 512 thr, grid 512 -> 2 blocks/CU (16 waves/CU).
//    Energy waves (mt=w&1, jq=w>>1): one 16x16 split tile/chunk, 2 acc chains.
//    PV waves: 64 channels, acc[4][2]. K prefetch for chunk+1 before barrier.
//  - proj: 512 thr on same 32-col tile -> 16 waves/CU; biases in LDS.
// Verified math from round 3 retained: two-pass flash, split-bf16 exact
// energy, p rounded to bf16 with l summed from rounded p, O^T = V^T P^T.
// Dtype detection (round-2, verified) retained.
// ---------------------------------------------------------------------------

typedef __attribute__((ext_vector_type(8))) short bf16x8;
typedef __attribute__((ext_vector_type(4))) float f32x4;

__device__ __forceinline__ float bf2f(unsigned short u) {
  return __builtin_bit_cast(float, (unsigned int)u << 16);
}
__device__ __forceinline__ unsigned short f2bf(float f) {
  unsigned int u = __builtin_bit_cast(unsigned int, f);
  u = u + 0x7fffu + ((u >> 16) & 1u);   // RNE
  return (unsigned short)(u >> 16);
}
__device__ __forceinline__ float bflo(unsigned int u) {
  return __builtin_bit_cast(float, u << 16);
}

// Returns 1 if x looks like fp32 data, 0 if bf16. Wave-uniform, deterministic.
__device__ __forceinline__ int detect_fp32_mode(const void* xv) {
  const unsigned int* p = (const unsigned int*)xv;
  const int lane = threadIdx.x & 63;
  const unsigned int w0 = p[lane];
  const unsigned int w1 = p[64 + lane];
  int cnt = 0;
  const unsigned short us[4] = {
      (unsigned short)(w0 & 0xffffu), (unsigned short)(w0 >> 16),
      (unsigned short)(w1 & 0xffffu), (unsigned short)(w1 >> 16)};
#pragma unroll
  for (int h = 0; h < 4; ++h) {
    const float a = fabsf(bf2f(us[h]));
    cnt += (a > 9.0e-13f && a < 32.0f) ? 1 : 0;
  }
#pragma unroll
  for (int mm = 32; mm >= 1; mm >>= 1) cnt += __shfl_xor(cnt, mm, 64);
  return cnt < 220;
}

// ---------------------------------------------------------------------------
// prep: canonicalize weights into ws as split hi/lo bf16; biases+gamma fp32.
// Wcat rows: wq[0:64) wqd[64:128) wk[128:192) wkd[192:256) wv[256:768).
// ---------------------------------------------------------------------------
__global__ __launch_bounds__(256) void prep_kernel(
    const void* wq, const void* bq, const void* wqd, const void* bqd,
    const void* wk, const void* bk, const void* wkd, const void* bkd,
    const void* wv, const void* bv, const void* gam, const void* x,
    unsigned short* __restrict__ Whi, unsigned short* __restrict__ Wlo,
    float* __restrict__ Bcat, float* __restrict__ gamF)
{
  const int fp32mode = detect_fp32_mode(x);
  const int row = blockIdx.x;                    // 0..767
  const void* src; const void* bsrc; int srow;
  if (row < 64)       { src = wq;  bsrc = bq;  srow = row; }
  else if (row < 128) { src = wqd; bsrc = bqd; srow = row - 64; }
  else if (row < 192) { src = wk;  bsrc = bk;  srow = row - 128; }
  else if (row < 256) { src = wkd; bsrc = bkd; srow = row - 192; }
  else                { src = wv;  bsrc = bv;  srow = row - 256; }
  for (int c = threadIdx.x; c < 512; c += 256) {
    const float v = fp32mode ? ((const float*)src)[(size_t)srow * 512 + c]
                             : bf2f(((const unsigned short*)src)[(size_t)srow * 512 + c]);
    const unsigned short h = f2bf(v);
    Whi[(size_t)row * 512 + c] = h;
    Wlo[(size_t)row * 512 + c] = f2bf(v - bf2f(h));
  }
  if (threadIdx.x == 0) {
    Bcat[row] = fp32mode ? ((const float*)bsrc)[srow]
                         : bf2f(((const unsigned short*)bsrc)[srow]);
    if (row == 0)
      gamF[0] = fp32mode ? ((const float*)gam)[0]
                         : bf2f(((const unsigned short*)gam)[0]);
  }
}

// ---------------------------------------------------------------------------
// Projection GEMM tile. C/D: col=lane&15 (n), row=quad*4+reg.
// kind 0: Q -> [b][n][128] hi/lo.  kind 1: K -> same layout, K pointers.
// kind 2: V -> [b][c][4096] bf16.
// ---------------------------------------------------------------------------
__device__ __forceinline__ void do_tile(
    const unsigned short* __restrict__ Whi, const unsigned short* __restrict__ Wlo,
    const float* bsh,
    const unsigned short* Xhi, const unsigned short* Xlo, int fp32mode,
    int wrow0, int kind, int d0,
    int b, int n0, int nsub, int l15, int quad,
    unsigned short* __restrict__ Qhi, unsigned short* __restrict__ Qlo,
    unsigned short* __restrict__ Khi, unsigned short* __restrict__ Klo,
    unsigned short* __restrict__ V)
{
  f32x4 acc;
#pragma unroll
  for (int r = 0; r < 4; ++r) acc[r] = bsh[wrow0 + quad * 4 + r];
  const unsigned short* whi = Whi + (size_t)(wrow0 + l15) * 512;
  const unsigned short* wlo = Wlo + (size_t)(wrow0 + l15) * 512;
  const unsigned short* xhi = Xhi + (nsub * 16 + l15) * 520;
  const unsigned short* xlo = Xlo + (nsub * 16 + l15) * 520;
#pragma unroll
  for (int ks = 0; ks < 16; ++ks) {
    const bf16x8 ah = *(const bf16x8*)(whi + ks * 32 + quad * 8);
    const bf16x8 bh = *(const bf16x8*)(xhi + ks * 32 + quad * 8);
    acc = __builtin_amdgcn_mfma_f32_16x16x32_bf16(ah, bh, acc, 0, 0, 0);
    if (fp32mode) {
      const bf16x8 al_ = *(const bf16x8*)(wlo + ks * 32 + quad * 8);
      const bf16x8 bl  = *(const bf16x8*)(xlo + ks * 32 + quad * 8);
      acc = __builtin_amdgcn_mfma_f32_16x16x32_bf16(ah, bl, acc, 0, 0, 0);
      acc = __builtin_amdgcn_mfma_f32_16x16x32_bf16(al_, bh, acc, 0, 0, 0);
    }
  }
  const int n = n0 + nsub * 16 + l15;
  if (kind <= 1) {                     // Q or K: [b][n][128] hi/lo
    ushort4 h, l;
#pragma unroll
    for (int r = 0; r < 4; ++r) {
      const float f = acc[r];
      const unsigned short hh = f2bf(f);
      ((unsigned short*)&h)[r] = hh;
      ((unsigned short*)&l)[r] = f2bf(f - bf2f(hh));
    }
    const size_t base = (((size_t)b << 12) + n) * 128 + d0 + quad * 4;
    if (kind == 0) { *(ushort4*)(Qhi + base) = h; *(ushort4*)(Qlo + base) = l; }
    else           { *(ushort4*)(Khi + base) = h; *(ushort4*)(Klo + base) = l; }
  } else {                             // V: [b][c][4096]
#pragma unroll
    for (int r = 0; r < 4; ++r)
      V[(((size_t)b * 512 + d0 + quad * 4 + r) << 12) + n] = f2bf(acc[r]);
  }
}

__global__ __launch_bounds__(512, 4) void proj_kernel(
    const void* __restrict__ x, const void* __restrict__ dep,
    const unsigned short* __restrict__ Whi, const unsigned short* __restrict__ Wlo,
    const float* __restrict__ Bcat,
    unsigned short* __restrict__ Qhi, unsigned short* __restrict__ Qlo,
    unsigned short* __restrict__ Khi, unsigned short* __restrict__ Klo,
    unsigned short* __restrict__ V)
{
  __shared__ unsigned short Xhi[32 * 520];   // 33.3 KB
  __shared__ unsigned short Xlo[32 * 520];
  __shared__ float bsh[768];                 // 3 KB
  const int fp32mode = detect_fp32_mode(x);
  const int tid  = threadIdx.x;
  const int lane = tid & 63;
  const int wave = tid >> 6;           // 0..7
  const int l15  = lane & 15;
  const int quad = lane >> 4;
  const int nsub = wave & 1;
  const int rgrp = wave >> 1;          // 0..3
  const int b  = blockIdx.y;
  const int n0 = blockIdx.x * 32;

  const int cbase = tid >> 4;          // 0..31
  const int nn    = (tid & 15) * 2;

  for (int i = tid; i < 768; i += 512) bsh[i] = Bcat[i];

  for (int r = 0; r < 16; ++r) {
    const int c = cbase + r * 32;
    const size_t off = (((size_t)b * 512 + c) << 12) + n0 + nn;
    float v0, v1;
    if (fp32mode) {
      const float2 f2 = *(const float2*)((const float*)x + off);
      v0 = f2.x; v1 = f2.y;
    } else {
      const unsigned int v2 = *(const unsigned int*)((const unsigned short*)x + off);
      v0 = bflo(v2 & 0xffffu); v1 = bflo(v2 >> 16);
    }
    const unsigned short h0 = f2bf(v0), h1 = f2bf(v1);
    Xhi[nn * 520 + c]       = h0;
    Xhi[(nn + 1) * 520 + c] = h1;
    Xlo[nn * 520 + c]       = f2bf(v0 - bf2f(h0));
    Xlo[(nn + 1) * 520 + c] = f2bf(v1 - bf2f(h1));
  }
  __syncthreads();

  // stage-1 (from x): 40 tiles = wq(4) | wk(4) | wv(32)
  for (int rt = rgrp; rt < 40; rt += 4) {
    if (rt < 4)
      do_tile(Whi, Wlo, bsh, Xhi, Xlo, fp32mode, rt * 16,             0, rt * 16,
              b, n0, nsub, l15, quad, Qhi, Qlo, Khi, Klo, V);
    else if (rt < 8)
      do_tile(Whi, Wlo, bsh, Xhi, Xlo, fp32mode, 128 + (rt - 4) * 16, 1, (rt - 4) * 16,
              b, n0, nsub, l15, quad, Qhi, Qlo, Khi, Klo, V);
    else
      do_tile(Whi, Wlo, bsh, Xhi, Xlo, fp32mode, 256 + (rt - 8) * 16, 2, (rt - 8) * 16,
              b, n0, nsub, l15, quad, Qhi, Qlo, Khi, Klo, V);
  }
  __syncthreads();

  for (int r = 0; r < 16; ++r) {
    const int c = cbase + r * 32;
    const size_t off = (((size_t)b * 512 + c) << 12) + n0 + nn;
    float v0, v1;
    if (fp32mode) {
      const float2 f2 = *(const float2*)((const float*)dep + off);
      v0 = f2.x; v1 = f2.y;
    } else {
      const unsigned int v2 = *(const unsigned int*)((const unsigned short*)dep + off);
      v0 = bflo(v2 & 0xffffu); v1 = bflo(v2 >> 16);
    }
    const unsigned short h0 = f2bf(v0), h1 = f2bf(v1);
    Xhi[nn * 520 + c]       = h0;
    Xhi[(nn + 1) * 520 + c] = h1;
    Xlo[nn * 520 + c]       = f2bf(v0 - bf2f(h0));
    Xlo[(nn + 1) * 520 + c] = f2bf(v1 - bf2f(h1));
  }
  __syncthreads();

  // stage-2 (from dep): wqd(4) | wkd(4), d-base 64
  for (int rt = rgrp; rt < 8; rt += 4) {
    if (rt < 4)
      do_tile(Whi, Wlo, bsh, Xhi, Xlo, fp32mode, 64 + rt * 16,        0, 64 + rt * 16,
              b, n0, nsub, l15, quad, Qhi, Qlo, Khi, Klo, V);
    else
      do_tile(Whi, Wlo, bsh, Xhi, Xlo, fp32mode, 192 + (rt - 4) * 16, 1, 64 + (rt - 4) * 16,
              b, n0, nsub, l15, quad, Qhi, Qlo, Khi, Klo, V);
  }
}

// ---------------------------------------------------------------------------
// MFMA flash attention. Block = (b, 32 Q-rows), 512 threads (8 waves),
// grid (128,4) = 512 blocks -> 2 blocks/CU.
// Energy wave (mt=w&1, jq=w>>1): 16x16 tile at j-quarter jq per 64-chunk.
// PV wave w: channels [w*64, w*64+64), acc[4][2].
// ---------------------------------------------------------------------------
__global__ __launch_bounds__(512, 4) void attn_kernel(
    const unsigned short* __restrict__ Qhi, const unsigned short* __restrict__ Qlo,
    const unsigned short* __restrict__ Khi, const unsigned short* __restrict__ Klo,
    const unsigned short* __restrict__ V,
    const void* __restrict__ x, const float* __restrict__ gamF,
    void* __restrict__ outp)
{
  __shared__ unsigned short Pbuf[2 * 32 * 72];   // 9.2 KB
  __shared__ float mstat[4 * 32];
  __shared__ float lstat[4 * 32];

  const int fp32mode = detect_fp32_mode(x);
  const int tid  = threadIdx.x;
  const int lane = tid & 63;
  const int w    = tid >> 6;          // 0..7
  const int l15  = lane & 15;
  const int quad = lane >> 4;
  const int mt   = w & 1;             // energy m-tile (16 rows)
  const int jq   = w >> 1;            // j-quarter 0..3
  const int b    = blockIdx.y;
  const int n0   = blockIdx.x * 32;
  const int c0   = w * 64;            // PV channel chunk

  // Q fragments (this wave's 16 energy rows), hi+lo
  bf16x8 qh[4], ql[4];
  {
    const size_t qb = (((size_t)b << 12) + n0 + mt * 16 + l15) * 128 + quad * 8;
#pragma unroll
    for (int ds = 0; ds < 4; ++ds) {
      qh[ds] = *(const bf16x8*)(Qhi + qb + ds * 32);
      ql[ds] = *(const bf16x8*)(Qlo + qb + ds * 32);
    }
  }

  // ---- pass 1: row maxima, hi-only energy, j-range jq*1024..+1024 ----
  float rmax[4] = {-3.0e38f, -3.0e38f, -3.0e38f, -3.0e38f};
  {
    const size_t kb = (((size_t)b << 12) + jq * 1024 + l15) * 128 + quad * 8;
    for (int t = 0; t < 64; t += 2) {
      const unsigned short* k0 = Khi + kb + (size_t)t * 2048;
      f32x4 e0 = {0.f, 0.f, 0.f, 0.f}, e1 = {0.f, 0.f, 0.f, 0.f};
#pragma unroll
      for (int ds = 0; ds < 4; ++ds) {
        const bf16x8 kf0 = *(const bf16x8*)(k0 + ds * 32);
        const bf16x8 kf1 = *(const bf16x8*)(k0 + 2048 + ds * 32);
        e0 = __builtin_amdgcn_mfma_f32_16x16x32_bf16(qh[ds], kf0, e0, 0, 0, 0);
        e1 = __builtin_amdgcn_mfma_f32_16x16x32_bf16(qh[ds], kf1, e1, 0, 0, 0);
      }
#pragma unroll
      for (int r = 0; r < 4; ++r) rmax[r] = fmaxf(rmax[r], fmaxf(e0[r], e1[r]));
    }
  }
#pragma unroll
  for (int r = 0; r < 4; ++r) {
#pragma unroll
    for (int mm = 8; mm >= 1; mm >>= 1)
      rmax[r] = fmaxf(rmax[r], __shfl_xor(rmax[r], mm, 64));
  }
  if (l15 == 0) {
#pragma unroll
    for (int r = 0; r < 4; ++r) mstat[jq * 32 + mt * 16 + quad * 4 + r] = rmax[r];
  }
  __syncthreads();
  float mh[4];
#pragma unroll
  for (int r = 0; r < 4; ++r) {
    const int i = mt * 16 + quad * 4 + r;
    mh[r] = fmaxf(fmaxf(mstat[i], mstat[32 + i]),
                  fmaxf(mstat[64 + i], mstat[96 + i]));
  }

  // ---- pass 2 ----
  float lpart[4] = {0.f, 0.f, 0.f, 0.f};
  f32x4 acc[4][2];
#pragma unroll
  for (int a = 0; a < 4; ++a)
#pragma unroll
    for (int bn = 0; bn < 2; ++bn) acc[a][bn] = (f32x4){0.f, 0.f, 0.f, 0.f};

  const int rowb = mt * 16 + quad * 4;
  size_t kq = (((size_t)b << 12) + jq * 16 + l15) * 128 + quad * 8;
  bf16x8 kh[4], kl[4];
#pragma unroll
  for (int ds = 0; ds < 4; ++ds) {
    kh[ds] = *(const bf16x8*)(Khi + kq + ds * 32);
    kl[ds] = *(const bf16x8*)(Klo + kq + ds * 32);
  }

  for (int chunk = 0; chunk < 64; ++chunk) {
    const int j0  = chunk * 64;
    const int buf = (chunk & 1) * 32 * 72;
    // energy 16x16 split tile; kh consumed first (frees regs for prefetch)
    f32x4 ea = {0.f, 0.f, 0.f, 0.f}, eb = {0.f, 0.f, 0.f, 0.f};
    ea = __builtin_amdgcn_mfma_f32_16x16x32_bf16(qh[0], kh[0], ea, 0, 0, 0);
    eb = __builtin_amdgcn_mfma_f32_16x16x32_bf16(qh[1], kh[1], eb, 0, 0, 0);
    ea = __builtin_amdgcn_mfma_f32_16x16x32_bf16(qh[2], kh[2], ea, 0, 0, 0);
    eb = __builtin_amdgcn_mfma_f32_16x16x32_bf16(qh[3], kh[3], eb, 0, 0, 0);
    ea = __builtin_amdgcn_mfma_f32_16x16x32_bf16(ql[0], kh[0], ea, 0, 0, 0);
    eb = __builtin_amdgcn_mfma_f32_16x16x32_bf16(ql[1], kh[1], eb, 0, 0, 0);
    ea = __builtin_amdgcn_mfma_f32_16x16x32_bf16(ql[2], kh[2], ea, 0, 0, 0);
    eb = __builtin_amdgcn_mfma_f32_16x16x32_bf16(ql[3], kh[3], eb, 0, 0, 0);
    ea = __builtin_amdgcn_mfma_f32_16x16x32_bf16(qh[0], kl[0], ea, 0, 0, 0);
    eb = __builtin_amdgcn_mfma_f32_16x16x32_bf16(qh[1], kl[1], eb, 0, 0, 0);
    ea = __builtin_amdgcn_mfma_f32_16x16x32_bf16(qh[2], kl[2], ea, 0, 0, 0);
    eb = __builtin_amdgcn_mfma_f32_16x16x32_bf16(qh[3], kl[3], eb, 0, 0, 0);
    // prefetch next chunk's K (lands during exp/LDS-write/barrier wait)
    if (chunk < 63) {
      kq += 8192;
#pragma unroll
      for (int ds = 0; ds < 4; ++ds) {
        kh[ds] = *(const bf16x8*)(Khi + kq + ds * 32);
        kl[ds] = *(const bf16x8*)(Klo + kq + ds * 32);
      }
    }
#pragma unroll
    for (int r = 0; r < 4; ++r) {
      const float p = __expf((ea[r] + eb[r]) - mh[r]);
      const unsigned short u = f2bf(p);
      lpart[r] += bf2f(u);              // l from ROUNDED p: exact norm
      Pbuf[buf + (rowb + r) * 72 + jq * 16 + l15] = u;
    }
    __syncthreads();
    // PV: O^T[c][i] += V^T[c][j] * P^T[j][i]
#pragma unroll
    for (int s = 0; s < 2; ++s) {
      bf16x8 pf[2];
#pragma unroll
      for (int nt = 0; nt < 2; ++nt)
        pf[nt] = *(const bf16x8*)(Pbuf + buf + (nt * 16 + l15) * 72 + s * 32 + quad * 8);
#pragma unroll
      for (int mc = 0; mc < 4; ++mc) {
        const size_t va_off =
            (((size_t)b * 512 + c0 + mc * 16 + l15) << 12) + j0 + s * 32 + quad * 8;
        const bf16x8 va = *(const bf16x8*)(V + va_off);
#pragma unroll
        for (int nt = 0; nt < 2; ++nt)
          acc[mc][nt] = __builtin_amdgcn_mfma_f32_16x16x32_bf16(va, pf[nt], acc[mc][nt], 0, 0, 0);
      }
    }
  }

  // ---- l reduction ----
#pragma unroll
  for (int r = 0; r < 4; ++r) {
#pragma unroll
    for (int mm = 8; mm >= 1; mm >>= 1)
      lpart[r] += __shfl_xor(lpart[r], mm, 64);
  }
  if (l15 == 0) {
#pragma unroll
    for (int r = 0; r < 4; ++r) lstat[jq * 32 + rowb + r] = lpart[r];
  }
  __syncthreads();

  // ---- epilogue: out[c][n] = gamma*O/l + x ----
  const float gv = gamF[0];
  float sc[2];
#pragma unroll
  for (int nt = 0; nt < 2; ++nt) {
    const int i = nt * 16 + l15;
    sc[nt] = gv / (lstat[i] + lstat[32 + i] + lstat[64 + i] + lstat[96 + i]);
  }
#pragma unroll
  for (int mc = 0; mc < 4; ++mc) {
#pragma unroll
    for (int r = 0; r < 4; ++r) {
      const int c_g = c0 + mc * 16 + quad * 4 + r;
      const size_t brow = ((size_t)b * 512 + c_g) << 12;
#pragma unroll
      for (int nt = 0; nt < 2; ++nt) {
        const size_t addr = brow + n0 + nt * 16 + l15;
        const float o = sc[nt] * acc[mc][nt][r];
        if (fp32mode) {
          ((float*)outp)[addr] = o + ((const float*)x)[addr];
        } else {
          ((unsigned short*)outp)[addr] =
              f2bf(o + bf2f(((const unsigned short*)x)[addr]));
        }
      }
    }
  }
}

extern "C" void kernel_launch(void* const* d_in, const int* in_sizes, int n_in,
                              void* d_out, int out_size, void* d_ws, size_t ws_size,
                              hipStream_t stream) {
  const void* x    = d_in[0];
  const void* dep  = d_in[1];
  const void* wq   = d_in[2];
  const void* bq   = d_in[3];
  const void* wqd  = d_in[4];
  const void* bqd  = d_in[5];
  const void* wk   = d_in[6];
  const void* bk   = d_in[7];
  const void* wkd  = d_in[8];
  const void* bkd  = d_in[9];
  const void* wv   = d_in[10];
  const void* bv   = d_in[11];
  const void* gam  = d_in[12];

  // ws: Whi(768K) Wlo(768K) Bcat gamF | @2M Qhi 4M | @6M Qlo 4M | @10M Khi 4M
  //     | @14M Klo 4M | @18M V 16M  (34 MB total)
  unsigned short* Whi = (unsigned short*)d_ws;
  unsigned short* Wlo = Whi + (size_t)768 * 512;
  float* Bcat = (float*)(Wlo + (size_t)768 * 512);
  float* gamF = Bcat + 768;
  unsigned short* Qhi = (unsigned short*)((char*)d_ws + ((size_t)2 << 20));
  unsigned short* Qlo = (unsigned short*)((char*)d_ws + ((size_t)6 << 20));
  unsigned short* Khi = (unsigned short*)((char*)d_ws + ((size_t)10 << 20));
  unsigned short* Klo = (unsigned short*)((char*)d_ws + ((size_t)14 << 20));
  unsigned short* V   = (unsigned short*)((char*)d_ws + ((size_t)18 << 20));

  prep_kernel<<<768, 256, 0, stream>>>(wq, bq, wqd, bqd, wk, bk, wkd, bkd,
                                       wv, bv, gam, x, Whi, Wlo, Bcat, gamF);
  proj_kernel<<<dim3(128, 4), 512, 0, stream>>>(x, dep, Whi, Wlo, Bcat,
                                                Qhi, Qlo, Khi, Klo, V);
  attn_kernel<<<dim3(128, 4), 512, 0, stream>>>(Qhi, Qlo, Khi, Klo, V, x, gamF, d_out);
}

// Round 5
// 729.446 us; speedup vs baseline: 1.3300x; 1.3300x over previous
//
#include <hip/hip_runtime.h>

// ---------------------------------------------------------------------------
// PAM_Module_Dep: dual-modality position attention. B=4, C=512, N=4096, CQ=64.
// Round 5: barrier-free flash attention.
//   Round-4 evidence: dur*MfmaUtil const (~56 us) at both 24% and 47%
//   occupancy => barrier-synchronized stalls dominate; the P LDS exchange
//   between energy-waves and PV-waves is structural. Fix: E^T = K*Q^T so
//   C/D lands with n=i; wave-PRIVATE LDS scratch transposes P^T into the
//   PV B-operand (no barrier, lgkmcnt only). Each wave: 32 rows x 512 ch x
//   j-half, acc in 256 AGPRs, 1 wave/SIMD, zero main-loop barriers.
// Verified math retained: two-pass flash (hi-only m-hat), split-bf16 exact
// energy (hh+hl+lh), p rounded to bf16 with l summed from rounded p,
// O^T = V^T * P^T, out = gamma*O/l + x. Dtype detection retained.
// ---------------------------------------------------------------------------

typedef __attribute__((ext_vector_type(8))) short bf16x8;
typedef __attribute__((ext_vector_type(4))) float f32x4;

__device__ __forceinline__ float bf2f(unsigned short u) {
  return __builtin_bit_cast(float, (unsigned int)u << 16);
}
__device__ __forceinline__ unsigned short f2bf(float f) {
  unsigned int u = __builtin_bit_cast(unsigned int, f);
  u = u + 0x7fffu + ((u >> 16) & 1u);   // RNE
  return (unsigned short)(u >> 16);
}
__device__ __forceinline__ float bflo(unsigned int u) {
  return __builtin_bit_cast(float, u << 16);
}

// Returns 1 if x looks like fp32 data, 0 if bf16. Wave-uniform, deterministic.
__device__ __forceinline__ int detect_fp32_mode(const void* xv) {
  const unsigned int* p = (const unsigned int*)xv;
  const int lane = threadIdx.x & 63;
  const unsigned int w0 = p[lane];
  const unsigned int w1 = p[64 + lane];
  int cnt = 0;
  const unsigned short us[4] = {
      (unsigned short)(w0 & 0xffffu), (unsigned short)(w0 >> 16),
      (unsigned short)(w1 & 0xffffu), (unsigned short)(w1 >> 16)};
#pragma unroll
  for (int h = 0; h < 4; ++h) {
    const float a = fabsf(bf2f(us[h]));
    cnt += (a > 9.0e-13f && a < 32.0f) ? 1 : 0;
  }
#pragma unroll
  for (int mm = 32; mm >= 1; mm >>= 1) cnt += __shfl_xor(cnt, mm, 64);
  return cnt < 220;
}

// ---------------------------------------------------------------------------
// prep: canonicalize weights into ws as split hi/lo bf16; biases+gamma fp32.
// ---------------------------------------------------------------------------
__global__ __launch_bounds__(256) void prep_kernel(
    const void* wq, const void* bq, const void* wqd, const void* bqd,
    const void* wk, const void* bk, const void* wkd, const void* bkd,
    const void* wv, const void* bv, const void* gam, const void* x,
    unsigned short* __restrict__ Whi, unsigned short* __restrict__ Wlo,
    float* __restrict__ Bcat, float* __restrict__ gamF)
{
  const int fp32mode = detect_fp32_mode(x);
  const int row = blockIdx.x;                    // 0..767
  const void* src; const void* bsrc; int srow;
  if (row < 64)       { src = wq;  bsrc = bq;  srow = row; }
  else if (row < 128) { src = wqd; bsrc = bqd; srow = row - 64; }
  else if (row < 192) { src = wk;  bsrc = bk;  srow = row - 128; }
  else if (row < 256) { src = wkd; bsrc = bkd; srow = row - 192; }
  else                { src = wv;  bsrc = bv;  srow = row - 256; }
  for (int c = threadIdx.x; c < 512; c += 256) {
    const float v = fp32mode ? ((const float*)src)[(size_t)srow * 512 + c]
                             : bf2f(((const unsigned short*)src)[(size_t)srow * 512 + c]);
    const unsigned short h = f2bf(v);
    Whi[(size_t)row * 512 + c] = h;
    Wlo[(size_t)row * 512 + c] = f2bf(v - bf2f(h));
  }
  if (threadIdx.x == 0) {
    Bcat[row] = fp32mode ? ((const float*)bsrc)[srow]
                         : bf2f(((const unsigned short*)bsrc)[srow]);
    if (row == 0)
      gamF[0] = fp32mode ? ((const float*)gam)[0]
                         : bf2f(((const unsigned short*)gam)[0]);
  }
}

// ---------------------------------------------------------------------------
// Projection tile, BOTH 16-col subtiles per W-fragment load (halves W traffic,
// 2x MFMA per load latency). C/D: col=lane&15 (n), row=quad*4+reg.
// ---------------------------------------------------------------------------
__device__ __forceinline__ void do_tile2(
    const unsigned short* __restrict__ Whi, const unsigned short* __restrict__ Wlo,
    const float* bsh,
    const unsigned short* Xhi, const unsigned short* Xlo, int fp32mode,
    int wrow0, int kind, int d0,
    int b, int n0, int l15, int quad,
    unsigned short* __restrict__ Qhi, unsigned short* __restrict__ Qlo,
    unsigned short* __restrict__ Khi, unsigned short* __restrict__ Klo,
    unsigned short* __restrict__ V)
{
  f32x4 a0, a1;
#pragma unroll
  for (int r = 0; r < 4; ++r) a0[r] = a1[r] = bsh[wrow0 + quad * 4 + r];
  const unsigned short* whi = Whi + (size_t)(wrow0 + l15) * 512;
  const unsigned short* wlo = Wlo + (size_t)(wrow0 + l15) * 512;
  const unsigned short* x0h = Xhi + l15 * 520;
  const unsigned short* x1h = Xhi + (16 + l15) * 520;
  const unsigned short* x0l = Xlo + l15 * 520;
  const unsigned short* x1l = Xlo + (16 + l15) * 520;
#pragma unroll
  for (int ks = 0; ks < 16; ++ks) {
    const int o = ks * 32 + quad * 8;
    const bf16x8 ah = *(const bf16x8*)(whi + o);
    const bf16x8 b0 = *(const bf16x8*)(x0h + o);
    const bf16x8 b1 = *(const bf16x8*)(x1h + o);
    a0 = __builtin_amdgcn_mfma_f32_16x16x32_bf16(ah, b0, a0, 0, 0, 0);
    a1 = __builtin_amdgcn_mfma_f32_16x16x32_bf16(ah, b1, a1, 0, 0, 0);
    if (fp32mode) {
      const bf16x8 al_ = *(const bf16x8*)(wlo + o);
      const bf16x8 c0 = *(const bf16x8*)(x0l + o);
      const bf16x8 c1 = *(const bf16x8*)(x1l + o);
      a0 = __builtin_amdgcn_mfma_f32_16x16x32_bf16(ah, c0, a0, 0, 0, 0);
      a0 = __builtin_amdgcn_mfma_f32_16x16x32_bf16(al_, b0, a0, 0, 0, 0);
      a1 = __builtin_amdgcn_mfma_f32_16x16x32_bf16(ah, c1, a1, 0, 0, 0);
      a1 = __builtin_amdgcn_mfma_f32_16x16x32_bf16(al_, b1, a1, 0, 0, 0);
    }
  }
#pragma unroll
  for (int ns = 0; ns < 2; ++ns) {
    const f32x4 acc = ns ? a1 : a0;
    const int n = n0 + ns * 16 + l15;
    if (kind <= 1) {                     // Q or K: [b][n][128] hi/lo
      ushort4 h, l;
#pragma unroll
      for (int r = 0; r < 4; ++r) {
        const float f = acc[r];
        const unsigned short hh = f2bf(f);
        ((unsigned short*)&h)[r] = hh;
        ((unsigned short*)&l)[r] = f2bf(f - bf2f(hh));
      }
      const size_t base = (((size_t)b << 12) + n) * 128 + d0 + quad * 4;
      if (kind == 0) { *(ushort4*)(Qhi + base) = h; *(ushort4*)(Qlo + base) = l; }
      else           { *(ushort4*)(Khi + base) = h; *(ushort4*)(Klo + base) = l; }
    } else {                             // V: [b][c][4096]
#pragma unroll
      for (int r = 0; r < 4; ++r)
        V[(((size_t)b * 512 + d0 + quad * 4 + r) << 12) + n] = f2bf(acc[r]);
    }
  }
}

__global__ __launch_bounds__(512, 4) void proj_kernel(
    const void* __restrict__ x, const void* __restrict__ dep,
    const unsigned short* __restrict__ Whi, const unsigned short* __restrict__ Wlo,
    const float* __restrict__ Bcat,
    unsigned short* __restrict__ Qhi, unsigned short* __restrict__ Qlo,
    unsigned short* __restrict__ Khi, unsigned short* __restrict__ Klo,
    unsigned short* __restrict__ V)
{
  __shared__ unsigned short Xhi[32 * 520];   // 33.3 KB
  __shared__ unsigned short Xlo[32 * 520];
  __shared__ float bsh[768];
  const int fp32mode = detect_fp32_mode(x);
  const int tid  = threadIdx.x;
  const int lane = tid & 63;
  const int w    = tid >> 6;           // 0..7
  const int l15  = lane & 15;
  const int quad = lane >> 4;
  const int b  = blockIdx.y;
  const int n0 = blockIdx.x * 32;

  const int cbase = tid >> 4;          // 0..31
  const int nn    = (tid & 15) * 2;

  for (int i = tid; i < 768; i += 512) bsh[i] = Bcat[i];

  for (int r = 0; r < 16; ++r) {
    const int c = cbase + r * 32;
    const size_t off = (((size_t)b * 512 + c) << 12) + n0 + nn;
    float v0, v1;
    if (fp32mode) {
      const float2 f2 = *(const float2*)((const float*)x + off);
      v0 = f2.x; v1 = f2.y;
    } else {
      const unsigned int v2 = *(const unsigned int*)((const unsigned short*)x + off);
      v0 = bflo(v2 & 0xffffu); v1 = bflo(v2 >> 16);
    }
    const unsigned short h0 = f2bf(v0), h1 = f2bf(v1);
    Xhi[nn * 520 + c]       = h0;
    Xhi[(nn + 1) * 520 + c] = h1;
    Xlo[nn * 520 + c]       = f2bf(v0 - bf2f(h0));
    Xlo[(nn + 1) * 520 + c] = f2bf(v1 - bf2f(h1));
  }
  __syncthreads();

  // stage-1 (from x): 40 tiles = wq(4) | wk(4) | wv(32); wave stride 8
  for (int rt = w; rt < 40; rt += 8) {
    if (rt < 4)
      do_tile2(Whi, Wlo, bsh, Xhi, Xlo, fp32mode, rt * 16,             0, rt * 16,
               b, n0, l15, quad, Qhi, Qlo, Khi, Klo, V);
    else if (rt < 8)
      do_tile2(Whi, Wlo, bsh, Xhi, Xlo, fp32mode, 128 + (rt - 4) * 16, 1, (rt - 4) * 16,
               b, n0, l15, quad, Qhi, Qlo, Khi, Klo, V);
    else
      do_tile2(Whi, Wlo, bsh, Xhi, Xlo, fp32mode, 256 + (rt - 8) * 16, 2, (rt - 8) * 16,
               b, n0, l15, quad, Qhi, Qlo, Khi, Klo, V);
  }
  __syncthreads();

  for (int r = 0; r < 16; ++r) {
    const int c = cbase + r * 32;
    const size_t off = (((size_t)b * 512 + c) << 12) + n0 + nn;
    float v0, v1;
    if (fp32mode) {
      const float2 f2 = *(const float2*)((const float*)dep + off);
      v0 = f2.x; v1 = f2.y;
    } else {
      const unsigned int v2 = *(const unsigned int*)((const unsigned short*)dep + off);
      v0 = bflo(v2 & 0xffffu); v1 = bflo(v2 >> 16);
    }
    const unsigned short h0 = f2bf(v0), h1 = f2bf(v1);
    Xhi[nn * 520 + c]       = h0;
    Xhi[(nn + 1) * 520 + c] = h1;
    Xlo[nn * 520 + c]       = f2bf(v0 - bf2f(h0));
    Xlo[(nn + 1) * 520 + c] = f2bf(v1 - bf2f(h1));
  }
  __syncthreads();

  // stage-2 (from dep): wqd(4) | wkd(4), one tile per wave, d-base 64
  {
    const int rt = w;
    if (rt < 4)
      do_tile2(Whi, Wlo, bsh, Xhi, Xlo, fp32mode, 64 + rt * 16,        0, 64 + rt * 16,
               b, n0, l15, quad, Qhi, Qlo, Khi, Klo, V);
    else
      do_tile2(Whi, Wlo, bsh, Xhi, Xlo, fp32mode, 192 + (rt - 4) * 16, 1, 64 + (rt - 4) * 16,
               b, n0, l15, quad, Qhi, Qlo, Khi, Klo, V);
  }
}

// ---------------------------------------------------------------------------
// Barrier-free MFMA flash attention.
// Grid: 256 blocks x 256 thr (4 waves). Block covers 64 rows of one batch.
//   id bits: xcd = id&7 = 2b + s  (batch-per-XCD-pair L2 locality)
//   wave w: ic = w&1 (32-row chunk), jh = w>>1 (j-half).
// Wave: E^T = K*Q^T (split exact) -> exp -> wave-private LDS transpose ->
//       O^T += V^T * P^T over all 512 channels. acc[32][2] = 256 AGPRs.
// Barriers: 1 (pass-1 max combine) + 1 (jh pair reduction). None in loop.
// ---------------------------------------------------------------------------
__global__ __launch_bounds__(256, 1) void attn_kernel(
    const unsigned short* __restrict__ Qhi, const unsigned short* __restrict__ Qlo,
    const unsigned short* __restrict__ Khi, const unsigned short* __restrict__ Klo,
    const unsigned short* __restrict__ V,
    const void* __restrict__ x, const float* __restrict__ gamF,
    void* __restrict__ outp)
{
  __shared__ float red[2][32][516];               // 132 KB pair-reduction
  __shared__ unsigned short pscr[4][2][16 * 40];  // 10.2 KB wave-private P^T
  __shared__ float mstat[2][2][32];
  __shared__ float lstat[2][2][32];

  const int fp32mode = detect_fp32_mode(x);
  const int tid  = threadIdx.x;
  const int lane = tid & 63;
  const int w    = tid >> 6;          // 0..3
  const int l15  = lane & 15;
  const int quad = lane >> 4;
  const int ic   = w & 1;
  const int jh   = w >> 1;
  const int id   = blockIdx.x;
  const int b    = (id >> 1) & 3;
  const int n0   = (((id >> 3) << 1) | (id & 1)) * 64;

  // Q fragments: 2 i-tiles (32 rows), hi+lo
  bf16x8 qh[2][4], ql[2][4];
#pragma unroll
  for (int it = 0; it < 2; ++it) {
    const size_t qb = (((size_t)b << 12) + n0 + ic * 32 + it * 16 + l15) * 128 + quad * 8;
#pragma unroll
    for (int ds = 0; ds < 4; ++ds) {
      qh[it][ds] = *(const bf16x8*)(Qhi + qb + ds * 32);
      ql[it][ds] = *(const bf16x8*)(Qlo + qb + ds * 32);
    }
  }

  // ---- pass 1: row maxima over this j-half, hi-only E^T ----
  float rm[2] = {-3.0e38f, -3.0e38f};
  {
    const size_t kb0 = (((size_t)b << 12) + jh * 2048 + l15) * 128 + quad * 8;
    for (int t = 0; t < 128; t += 2) {
      const unsigned short* ka = Khi + kb0 + (size_t)t * 2048;
      f32x4 e0[2], e1[2];
#pragma unroll
      for (int it = 0; it < 2; ++it) { e0[it] = (f32x4){0.f,0.f,0.f,0.f}; e1[it] = (f32x4){0.f,0.f,0.f,0.f}; }
#pragma unroll
      for (int ds = 0; ds < 4; ++ds) {
        const bf16x8 kfa = *(const bf16x8*)(ka + ds * 32);
        const bf16x8 kfb = *(const bf16x8*)(ka + 2048 + ds * 32);
#pragma unroll
        for (int it = 0; it < 2; ++it) {
          e0[it] = __builtin_amdgcn_mfma_f32_16x16x32_bf16(kfa, qh[it][ds], e0[it], 0, 0, 0);
          e1[it] = __builtin_amdgcn_mfma_f32_16x16x32_bf16(kfb, qh[it][ds], e1[it], 0, 0, 0);
        }
      }
#pragma unroll
      for (int it = 0; it < 2; ++it)
#pragma unroll
        for (int r = 0; r < 4; ++r)
          rm[it] = fmaxf(rm[it], fmaxf(e0[it][r], e1[it][r]));
    }
  }
#pragma unroll
  for (int it = 0; it < 2; ++it) {
    rm[it] = fmaxf(rm[it], __shfl_xor(rm[it], 16, 64));
    rm[it] = fmaxf(rm[it], __shfl_xor(rm[it], 32, 64));
    if (quad == 0) mstat[jh][ic][it * 16 + l15] = rm[it];
  }
  __syncthreads();
  float mh[2];
#pragma unroll
  for (int it = 0; it < 2; ++it)
    mh[it] = fmaxf(mstat[0][ic][it * 16 + l15], mstat[1][ic][it * 16 + l15]);

  // ---- pass 2: barrier-free main loop ----
  f32x4 acc[32][2];
#pragma unroll
  for (int ct = 0; ct < 32; ++ct)
#pragma unroll
    for (int it = 0; it < 2; ++it) acc[ct][it] = (f32x4){0.f, 0.f, 0.f, 0.f};
  float lpart[2] = {0.f, 0.f};

  unsigned short* myscr = &pscr[w][0][0];           // [it][i=l15][40 j-shorts]
  const unsigned short* vbase =
      V + (((size_t)b * 512 + l15) << 12) + quad * 8;

  for (int itr = 0; itr < 64; ++itr) {
    const int j0 = jh * 2048 + itr * 32;
    // K fragments for two 16-j tiles
    const size_t kb = (((size_t)b << 12) + j0 + l15) * 128 + quad * 8;
    bf16x8 kh[2][4], kl[2][4];
#pragma unroll
    for (int t = 0; t < 2; ++t)
#pragma unroll
      for (int ds = 0; ds < 4; ++ds) {
        kh[t][ds] = *(const bf16x8*)(Khi + kb + t * 2048 + ds * 32);
        kl[t][ds] = *(const bf16x8*)(Klo + kb + t * 2048 + ds * 32);
      }
    // split-exact E^T: e = K*Q^T (hh + hl + lh)
    f32x4 e[2][2];
#pragma unroll
    for (int it = 0; it < 2; ++it)
#pragma unroll
      for (int t = 0; t < 2; ++t) e[it][t] = (f32x4){0.f, 0.f, 0.f, 0.f};
#pragma unroll
    for (int ds = 0; ds < 4; ++ds)
#pragma unroll
      for (int t = 0; t < 2; ++t)
#pragma unroll
        for (int it = 0; it < 2; ++it)
          e[it][t] = __builtin_amdgcn_mfma_f32_16x16x32_bf16(kh[t][ds], qh[it][ds], e[it][t], 0, 0, 0);
#pragma unroll
    for (int ds = 0; ds < 4; ++ds)
#pragma unroll
      for (int t = 0; t < 2; ++t)
#pragma unroll
        for (int it = 0; it < 2; ++it) {
          e[it][t] = __builtin_amdgcn_mfma_f32_16x16x32_bf16(kh[t][ds], ql[it][ds], e[it][t], 0, 0, 0);
          e[it][t] = __builtin_amdgcn_mfma_f32_16x16x32_bf16(kl[t][ds], qh[it][ds], e[it][t], 0, 0, 0);
        }
    // exp -> bf16 p -> wave-private scratch [i][j_local] (stride 40 shorts)
#pragma unroll
    for (int it = 0; it < 2; ++it)
#pragma unroll
      for (int t = 0; t < 2; ++t) {
        const float p0 = __expf(e[it][t][0] - mh[it]);
        const float p1 = __expf(e[it][t][1] - mh[it]);
        const float p2 = __expf(e[it][t][2] - mh[it]);
        const float p3 = __expf(e[it][t][3] - mh[it]);
        const unsigned short u0 = f2bf(p0), u1 = f2bf(p1);
        const unsigned short u2 = f2bf(p2), u3 = f2bf(p3);
        lpart[it] += (bf2f(u0) + bf2f(u1)) + (bf2f(u2) + bf2f(u3));
        unsigned int* dst = (unsigned int*)(myscr + it * 640 + l15 * 40 + t * 16 + quad * 4);
        dst[0] = (unsigned int)u0 | ((unsigned int)u1 << 16);
        dst[1] = (unsigned int)u2 | ((unsigned int)u3 << 16);
      }
    // read P^T B-frags: lane(quad,l15): k=j_local=quad*8+jj, n=i=l15
    bf16x8 pf[2];
#pragma unroll
    for (int it = 0; it < 2; ++it)
      pf[it] = *(const bf16x8*)(myscr + it * 640 + l15 * 40 + quad * 8);
    // PV: O^T[c][i] += V^T[c][j] * P^T[j][i] over all 512 channels
    const unsigned short* vp = vbase + j0;
#pragma unroll
    for (int ct = 0; ct < 32; ++ct) {
      const bf16x8 va = *(const bf16x8*)(vp + ((size_t)ct << 16));
      acc[ct][0] = __builtin_amdgcn_mfma_f32_16x16x32_bf16(va, pf[0], acc[ct][0], 0, 0, 0);
      acc[ct][1] = __builtin_amdgcn_mfma_f32_16x16x32_bf16(va, pf[1], acc[ct][1], 0, 0, 0);
    }
  }

  // ---- l reduction + jh pair reduction ----
#pragma unroll
  for (int it = 0; it < 2; ++it) {
    float lp = lpart[it];
    lp += __shfl_xor(lp, 16, 64);
    lp += __shfl_xor(lp, 32, 64);
    if (quad == 0) lstat[jh][ic][it * 16 + l15] = lp;
  }
  if (jh == 1) {
#pragma unroll
    for (int ct = 0; ct < 32; ++ct)
#pragma unroll
      for (int it = 0; it < 2; ++it)
        *(f32x4*)&red[ic][it * 16 + l15][ct * 16 + quad * 4] = acc[ct][it];
  }
  __syncthreads();
  if (jh == 1) return;

  // ---- epilogue (jh==0 waves): out[c][n] = gamma*O/l + x ----
#pragma unroll
  for (int ct = 0; ct < 32; ++ct)
#pragma unroll
    for (int it = 0; it < 2; ++it) {
      const f32x4 o = *(const f32x4*)&red[ic][it * 16 + l15][ct * 16 + quad * 4];
      acc[ct][it] += o;
    }
  const float gv = gamF[0];
  float sc[2];
#pragma unroll
  for (int it = 0; it < 2; ++it) {
    const float l = lstat[0][ic][it * 16 + l15] + lstat[1][ic][it * 16 + l15];
    sc[it] = gv / l;
  }
#pragma unroll
  for (int ct = 0; ct < 32; ++ct)
#pragma unroll
    for (int r = 0; r < 4; ++r) {
      const int c_g = ct * 16 + quad * 4 + r;
      const size_t brow = ((size_t)b * 512 + c_g) << 12;
#pragma unroll
      for (int it = 0; it < 2; ++it) {
        const size_t addr = brow + n0 + ic * 32 + it * 16 + l15;
        const float o = sc[it] * acc[ct][it][r];
        if (fp32mode) {
          ((float*)outp)[addr] = o + ((const float*)x)[addr];
        } else {
          ((unsigned short*)outp)[addr] =
              f2bf(o + bf2f(((const unsigned short*)x)[addr]));
        }
      }
    }
}

extern "C" void kernel_launch(void* const* d_in, const int* in_sizes, int n_in,
                              void* d_out, int out_size, void* d_ws, size_t ws_size,
                              hipStream_t stream) {
  const void* x    = d_in[0];
  const void* dep  = d_in[1];
  const void* wq   = d_in[2];
  const void* bq   = d_in[3];
  const void* wqd  = d_in[4];
  const void* bqd  = d_in[5];
  const void* wk   = d_in[6];
  const void* bk   = d_in[7];
  const void* wkd  = d_in[8];
  const void* bkd  = d_in[9];
  const void* wv   = d_in[10];
  const void* bv   = d_in[11];
  const void* gam  = d_in[12];

  // ws: Whi(768K) Wlo(768K) Bcat gamF | @2M Qhi 4M | @6M Qlo 4M | @10M Khi 4M
  //     | @14M Klo 4M | @18M V 16M  (34 MB total)
  unsigned short* Whi = (unsigned short*)d_ws;
  unsigned short* Wlo = Whi + (size_t)768 * 512;
  float* Bcat = (float*)(Wlo + (size_t)768 * 512);
  float* gamF = Bcat + 768;
  unsigned short* Qhi = (unsigned short*)((char*)d_ws + ((size_t)2 << 20));
  unsigned short* Qlo = (unsigned short*)((char*)d_ws + ((size_t)6 << 20));
  unsigned short* Khi = (unsigned short*)((char*)d_ws + ((size_t)10 << 20));
  unsigned short* Klo = (unsigned short*)((char*)d_ws + ((size_t)14 << 20));
  unsigned short* V   = (unsigned short*)((char*)d_ws + ((size_t)18 << 20));

  prep_kernel<<<768, 256, 0, stream>>>(wq, bq, wqd, bqd, wk, bk, wkd, bkd,
                                       wv, bv, gam, x, Whi, Wlo, Bcat, gamF);
  proj_kernel<<<dim3(128, 4), 512, 0, stream>>>(x, dep, Whi, Wlo, Bcat,
                                                Qhi, Qlo, Khi, Klo, V);
  attn_kernel<<<256, 256, 0, stream>>>(Qhi, Qlo, Khi, Klo, V, x, gamF, d_out);
}